// Round 18
// baseline (455.125 us; speedup 1.0000x reference)
//
#include <hip/hip_runtime.h>
#include <math.h>

#define HH 96
#define WW 96
#define NN (HH*WW)
#define RAD 30
#define TOTPAIRS 24265476   // sum over pixels of window area = 4926*4926

// ---- numpy's f32 SIMD exp (r13-verified): rational P5/Q2, Cody-Waite, FMA Horner,
// IEEE divide, scalef. ----
__device__ __forceinline__ float np_expf(float x) {
    float q = __builtin_rintf(x * 1.442695040888963f);
    float r = fmaf(q, -6.93145752e-1f, x);
    r = fmaf(q, -1.42860677e-6f, r);
    float num = 5.082762527590693718096e-04f;
    num = fmaf(num, r, 6.757896990527504603057e-03f);
    num = fmaf(num, r, 5.114512081637298353406e-02f);
    num = fmaf(num, r, 2.473615434895520810817e-01f);
    num = fmaf(num, r, 7.257664613233124478488e-01f);
    num = fmaf(num, r, 9.999999999980870924916e-01f);
    float den = 2.159509375685829852307e-02f;
    den = fmaf(den, r, -2.742335390411667452936e-01f);
    den = fmaf(den, r, 1.0f);
    float p = num / den;
    p = ldexpf(p, (int)q);
    if (x > 88.72283935546875f) p = __builtin_inff();
    if (x < -103.97208404541015625f) p = 0.0f;
    return p;
}

// Filter-only: x in [-42, 0] -> clamps provably dead (bit-exact on this domain).
__device__ __forceinline__ float np_expf_nc(float x) {
    float q = __builtin_rintf(x * 1.442695040888963f);
    float r = fmaf(q, -6.93145752e-1f, x);
    r = fmaf(q, -1.42860677e-6f, r);
    float num = 5.082762527590693718096e-04f;
    num = fmaf(num, r, 6.757896990527504603057e-03f);
    num = fmaf(num, r, 5.114512081637298353406e-02f);
    num = fmaf(num, r, 2.473615434895520810817e-01f);
    num = fmaf(num, r, 7.257664613233124478488e-01f);
    num = fmaf(num, r, 9.999999999980870924916e-01f);
    float den = 2.159509375685829852307e-02f;
    den = fmaf(den, r, -2.742335390411667452936e-01f);
    den = fmaf(den, r, 1.0f);
    float p = num / den;
    return ldexpf(p, (int)q);
}

// window helpers (square image): count and prefix-sum of window widths
__device__ __forceinline__ int wincnt(int x) {
    int lo = x - RAD; if (lo < 0) lo = 0;
    int hi = x + RAD; if (hi > 95) hi = 95;
    return hi - lo + 1;
}
__device__ __forceinline__ int cumwin(int x) {
    int g1 = (x <= 30) ? (30 * x - (x * (x - 1)) / 2) : 465;
    int g2 = (x <= 66) ? 0 : ((x - 66) * (x - 65)) / 2;
    return 61 * x - g1 - g2;
}

// ---------------- prep: byte-identical to r13 ----------------
__global__ __launch_bounds__(256) void crf_prep(const float* __restrict__ input,
                                                const float* __restrict__ ref,
                                                float4* __restrict__ colA,
                                                float4* __restrict__ qA,
                                                float* __restrict__ qB) {
#pragma clang fp contract(off)
    int n = blockIdx.x * 256 + threadIdx.x;
    if (n >= NN) return;
    int py = n / WW;
    int px = n - py * WW;
    float yb = (float)py / 5.0f;
    float xb = (float)px / 5.0f;
    float r2 = ref[0 * NN + n] * 2.0f;
    float g2 = ref[1 * NN + n] * 2.0f;
    float b2 = ref[2 * NN + n] * 2.0f;
    float sqg = yb * yb + xb * xb;
    float sqb = ((sqg + r2 * r2) + g2 * g2) + b2 * b2;
    colA[n] = make_float4(r2, g2, b2, sqb);
    float l0 = input[0 * NN + n], l1 = input[1 * NN + n], l2 = input[2 * NN + n];
    float l3 = input[3 * NN + n], l4 = input[4 * NN + n];
    float m = fmaxf(fmaxf(fmaxf(fmaxf(l0, l1), l2), l3), l4);
    float e0 = np_expf(l0 - m), e1 = np_expf(l1 - m), e2 = np_expf(l2 - m);
    float e3 = np_expf(l3 - m), e4 = np_expf(l4 - m);
    float s = (((e0 + e1) + e2) + e3) + e4;
    qA[n] = make_float4(e0 / s, e1 / s, e2 / s, e3 / s);
    qB[n] = e4 / s;
}

// Common geometry macro for the filter kernels (r17 mapping, center-out ordering)
#define FILTER_PREAMBLE                                                        \
    int tid = threadIdx.x;                                                     \
    int br = blockIdx.x / 12;                                                  \
    int bc = blockIdx.x - br * 12;                                             \
    int row = (br & 1) ? (48 + (br >> 1)) : (47 - (br >> 1));                  \
    int cg8 = (bc & 1) ? (6 + (bc >> 1)) : (5 - (bc >> 1));                    \
    int j = tid & 3;                                                           \
    int k = (tid >> 2) & 3;                                                    \
    int p = (tid >> 4) & 7;                                                    \
    int role = tid >> 7;                                                       \
    int py = row;                                                              \
    int px = cg8 * 8 + p;                                                      \
    int n0 = row * WW + px;                                                    \
    int ylo = py - RAD; if (ylo < 0) ylo = 0;                                  \
    int yhi = py + RAD; if (yhi > HH - 1) yhi = HH - 1;                        \
    int xlo = px - RAD; if (xlo < 0) xlo = 0;                                  \
    int xhi = px + RAD; if (xhi > WW - 1) xhi = WW - 1;                        \
    int res = k * 4 + j;                                                       \
    int cst = xlo + ((res - xlo) & 15);

// ---------------- filter+store: r17 filter, also writes per-pair weights ----------------
// Weight layout: per pixel n, base(n) = cumwin(py)*4926 + wincnt(py)*cumwin(px);
// floats at wts[2*base + role*area + (my-ylo)*winX + (mx-xlo)], row-major window.
// 16-lane groups touch contiguous 16-float segments per (my,t) -> coalesced.
__global__ __launch_bounds__(256) void crf_filter_store(const float4* __restrict__ colA,
                                                        const float4* __restrict__ qA,
                                                        const float* __restrict__ qB,
                                                        float* __restrict__ combF,
                                                        float* __restrict__ wts) {
#pragma clang fp contract(off)
    __shared__ float c5[HH];
    __shared__ float sq1[HH];
    __shared__ float cg[8][5];
    if (threadIdx.x < HH) {
        float v = (float)threadIdx.x / 5.0f;
        c5[threadIdx.x] = v;
        sq1[threadIdx.x] = v * v;
    }
    __syncthreads();
    FILTER_PREAMBLE
    float yn = c5[py], xn = c5[px];
    float sqg_n = sq1[py] + sq1[px];
    float4 cn = colA[n0];
    float sqb_n = cn.w;
    int winX = xhi - xlo + 1;
    int winY = yhi - ylo + 1;
    int base2 = 2 * (cumwin(py) * 4926 + winY * cumwin(px));
    float* wp = wts + base2 + role * (winY * winX);
    int coff = cst - xlo;

    float a0 = 0.f, a1 = 0.f, a2 = 0.f, a3 = 0.f, a4 = 0.f;
    if (role == 0) {
#pragma unroll 2
        for (int my = ylo; my <= yhi; ++my) {
            float ym = c5[my];
            float tyy = yn * ym;
            int rb = my * WW;
            float* wrow = wp + (my - ylo) * winX + coff;
            int t = 0;
            for (int mx = cst; mx <= xhi; mx += 16, ++t) {
                int m = rb + mx;
                float4 cm = colA[m];
                float4 f = qA[m];
                float fb = qB[m];
                float dot = tyy;
                dot = dot + xn * c5[mx];
                dot = dot + cn.x * cm.x;
                dot = dot + cn.y * cm.y;
                dot = dot + cn.z * cm.z;
                float d2 = (sqb_n + cm.w) - 2.0f * dot;
                d2 = fmaxf(d2, 0.0f);
                float w = np_expf_nc(-0.5f * d2);
                wrow[t * 16] = w;
                a0 = a0 + w * f.x;
                a1 = a1 + w * f.y;
                a2 = a2 + w * f.z;
                a3 = a3 + w * f.w;
                a4 = a4 + w * fb;
            }
        }
    } else {
#pragma unroll 2
        for (int my = ylo; my <= yhi; ++my) {
            float ym = c5[my];
            float tyy = yn * ym;
            float sqy = sq1[my];
            int rb = my * WW;
            float* wrow = wp + (my - ylo) * winX + coff;
            int t = 0;
            for (int mx = cst; mx <= xhi; mx += 16, ++t) {
                int m = rb + mx;
                float4 f = qA[m];
                float fb = qB[m];
                float dot = tyy;
                dot = dot + xn * c5[mx];
                float sqm = sqy + sq1[mx];
                float d2 = (sqg_n + sqm) - 2.0f * dot;
                d2 = fmaxf(d2, 0.0f);
                float w = np_expf_nc(-0.5f * d2);
                wrow[t * 16] = w;
                a0 = a0 + w * f.x;
                a1 = a1 + w * f.y;
                a2 = a2 + w * f.z;
                a3 = a3 + w * f.w;
                a4 = a4 + w * fb;
            }
        }
    }
    float r_[5] = {a0, a1, a2, a3, a4};
#pragma unroll
    for (int c = 0; c < 5; ++c) {
        float v = r_[c];
        v = v + __shfl_xor(v, 4);
        v = v + __shfl_xor(v, 8);
        v = v + __shfl_xor(v, 2);
        v = v + __shfl_xor(v, 1);
        r_[c] = v;
    }
    if (role == 1 && (tid & 15) == 0) {
#pragma unroll
        for (int c = 0; c < 5; ++c) cg[p][c] = r_[c];
    }
    __syncthreads();
    if (role == 0 && (tid & 15) == 0) {
#pragma unroll
        for (int c = 0; c < 5; ++c) combF[c * NN + n0] = r_[c] + cg[p][c];
    }
}

// ---------------- filter apply: load cached weights, identical accumulation chains ----------------
__global__ __launch_bounds__(256) void crf_filter_apply(const float4* __restrict__ qA,
                                                        const float* __restrict__ qB,
                                                        float* __restrict__ combF,
                                                        const float* __restrict__ wts) {
#pragma clang fp contract(off)
    __shared__ float cg[8][5];
    FILTER_PREAMBLE
    int winX = xhi - xlo + 1;
    int winY = yhi - ylo + 1;
    int base2 = 2 * (cumwin(py) * 4926 + winY * cumwin(px));
    const float* wp = wts + base2 + role * (winY * winX);
    int coff = cst - xlo;

    float a0 = 0.f, a1 = 0.f, a2 = 0.f, a3 = 0.f, a4 = 0.f;
#pragma unroll 2
    for (int my = ylo; my <= yhi; ++my) {
        int rb = my * WW;
        const float* wrow = wp + (my - ylo) * winX + coff;
        int t = 0;
        for (int mx = cst; mx <= xhi; mx += 16, ++t) {
            int m = rb + mx;
            float4 f = qA[m];
            float fb = qB[m];
            float w = wrow[t * 16];
            a0 = a0 + w * f.x;
            a1 = a1 + w * f.y;
            a2 = a2 + w * f.z;
            a3 = a3 + w * f.w;
            a4 = a4 + w * fb;
        }
    }
    float r_[5] = {a0, a1, a2, a3, a4};
#pragma unroll
    for (int c = 0; c < 5; ++c) {
        float v = r_[c];
        v = v + __shfl_xor(v, 4);
        v = v + __shfl_xor(v, 8);
        v = v + __shfl_xor(v, 2);
        v = v + __shfl_xor(v, 1);
        r_[c] = v;
    }
    if (role == 1 && (tid & 15) == 0) {
#pragma unroll
        for (int c = 0; c < 5; ++c) cg[p][c] = r_[c];
    }
    __syncthreads();
    if (role == 0 && (tid & 15) == 0) {
#pragma unroll
        for (int c = 0; c < 5; ++c) combF[c * NN + n0] = r_[c] + cg[p][c];
    }
}

// ---------------- fallback filter: r17 verbatim (no weight cache) ----------------
__global__ __launch_bounds__(256) void crf_filter(const float4* __restrict__ colA,
                                                  const float4* __restrict__ qA,
                                                  const float* __restrict__ qB,
                                                  float* __restrict__ combF) {
#pragma clang fp contract(off)
    __shared__ float c5[HH];
    __shared__ float sq1[HH];
    __shared__ float cg[8][5];
    if (threadIdx.x < HH) {
        float v = (float)threadIdx.x / 5.0f;
        c5[threadIdx.x] = v;
        sq1[threadIdx.x] = v * v;
    }
    __syncthreads();
    FILTER_PREAMBLE
    float yn = c5[py], xn = c5[px];
    float sqg_n = sq1[py] + sq1[px];
    float4 cn = colA[n0];
    float sqb_n = cn.w;

    float a0 = 0.f, a1 = 0.f, a2 = 0.f, a3 = 0.f, a4 = 0.f;
    if (role == 0) {
#pragma unroll 2
        for (int my = ylo; my <= yhi; ++my) {
            float ym = c5[my];
            float tyy = yn * ym;
            int rb = my * WW;
            for (int mx = cst; mx <= xhi; mx += 16) {
                int m = rb + mx;
                float4 cm = colA[m];
                float4 f = qA[m];
                float fb = qB[m];
                float dot = tyy;
                dot = dot + xn * c5[mx];
                dot = dot + cn.x * cm.x;
                dot = dot + cn.y * cm.y;
                dot = dot + cn.z * cm.z;
                float d2 = (sqb_n + cm.w) - 2.0f * dot;
                d2 = fmaxf(d2, 0.0f);
                float w = np_expf_nc(-0.5f * d2);
                a0 = a0 + w * f.x;
                a1 = a1 + w * f.y;
                a2 = a2 + w * f.z;
                a3 = a3 + w * f.w;
                a4 = a4 + w * fb;
            }
        }
    } else {
#pragma unroll 2
        for (int my = ylo; my <= yhi; ++my) {
            float ym = c5[my];
            float tyy = yn * ym;
            float sqy = sq1[my];
            int rb = my * WW;
            for (int mx = cst; mx <= xhi; mx += 16) {
                int m = rb + mx;
                float4 f = qA[m];
                float fb = qB[m];
                float dot = tyy;
                dot = dot + xn * c5[mx];
                float sqm = sqy + sq1[mx];
                float d2 = (sqg_n + sqm) - 2.0f * dot;
                d2 = fmaxf(d2, 0.0f);
                float w = np_expf_nc(-0.5f * d2);
                a0 = a0 + w * f.x;
                a1 = a1 + w * f.y;
                a2 = a2 + w * f.z;
                a3 = a3 + w * f.w;
                a4 = a4 + w * fb;
            }
        }
    }
    float r_[5] = {a0, a1, a2, a3, a4};
#pragma unroll
    for (int c = 0; c < 5; ++c) {
        float v = r_[c];
        v = v + __shfl_xor(v, 4);
        v = v + __shfl_xor(v, 8);
        v = v + __shfl_xor(v, 2);
        v = v + __shfl_xor(v, 1);
        r_[c] = v;
    }
    if (role == 1 && (tid & 15) == 0) {
#pragma unroll
        for (int c = 0; c < 5; ++c) cg[p][c] = r_[c];
    }
    __syncthreads();
    if (role == 0 && (tid & 15) == 0) {
#pragma unroll
        for (int c = 0; c < 5; ++c) combF[c * NN + n0] = r_[c] + cg[p][c];
    }
}

// ---------------- update: byte-identical to r13 ----------------
__global__ __launch_bounds__(256) void crf_update(const float* __restrict__ input,
                                                  const float* __restrict__ combF,
                                                  float4* __restrict__ qA,
                                                  float* __restrict__ qB,
                                                  float* __restrict__ outp,
                                                  int writeOut) {
#pragma clang fp contract(off)
    int n = blockIdx.x * 256 + threadIdx.x;
    if (n >= NN) return;
    int py = n / WW;
    int px = n - py * WW;
    float v[3][3][5];
#pragma unroll
    for (int ky = 0; ky < 3; ++ky) {
        int yy = py + ky - 1; yy = yy < 0 ? 0 : (yy > HH - 1 ? HH - 1 : yy);
#pragma unroll
        for (int kx = 0; kx < 3; ++kx) {
            int xx = px + kx - 1; xx = xx < 0 ? 0 : (xx > WW - 1 ? WW - 1 : xx);
            int m = yy * WW + xx;
#pragma unroll
            for (int c = 0; c < 5; ++c) v[ky][kx][c] = combF[c * NN + m];
        }
    }
    float l[5];
#pragma unroll
    for (int o = 0; o < 5; ++o) {
        float u = 0.f;
#pragma unroll
        for (int ky = 0; ky < 3; ++ky) {
#pragma unroll
            for (int kx = 0; kx < 3; ++kx) {
                float t = 0.f;
#pragma unroll
                for (int ci = 0; ci < 5; ++ci)
                    if (ci != o) t = t + v[ky][kx][ci];
                u = u + t;
            }
        }
        l[o] = input[o * NN + n] - 3.0f * u;
    }
    float m = fmaxf(fmaxf(fmaxf(fmaxf(l[0], l[1]), l[2]), l[3]), l[4]);
    float e0 = np_expf(l[0] - m), e1 = np_expf(l[1] - m), e2 = np_expf(l[2] - m);
    float e3 = np_expf(l[3] - m), e4 = np_expf(l[4] - m);
    float s = (((e0 + e1) + e2) + e3) + e4;
    float o0 = e0 / s, o1 = e1 / s, o2 = e2 / s, o3 = e3 / s, o4 = e4 / s;
    qA[n] = make_float4(o0, o1, o2, o3);
    qB[n] = o4;
    if (writeOut) {
        outp[0 * NN + n] = o0;
        outp[1 * NN + n] = o1;
        outp[2 * NN + n] = o2;
        outp[3 * NN + n] = o3;
        outp[4 * NN + n] = o4;
    }
}

extern "C" void kernel_launch(void* const* d_in, const int* in_sizes, int n_in,
                              void* d_out, int out_size, void* d_ws, size_t ws_size,
                              hipStream_t stream) {
    const float* input = (const float*)d_in[0];   // [1,5,96,96] f32
    const float* ref = (const float*)d_in[1];     // [1,3,96,96] f32
    float* ws = (float*)d_ws;
    float4* colA = (float4*)(ws + 0 * NN);        // 4*NN
    float4* qA = (float4*)(ws + 4 * NN);          // 4*NN
    float* qB = ws + 8 * NN;                      // NN
    float* combF = ws + 9 * NN;                   // 5*NN
    float* wts = ws + 14 * NN;                    // 2*TOTPAIRS (if ws is big enough)
    float* outp = (float*)d_out;

    size_t need = ((size_t)14 * NN + (size_t)2 * TOTPAIRS) * sizeof(float);
    crf_prep<<<36, 256, 0, stream>>>(input, ref, colA, qA, qB);
    if (ws_size >= need) {
        // iter 0 computes + stores weights and accumulates comb
        crf_filter_store<<<1152, 256, 0, stream>>>(colA, qA, qB, combF, wts);
        crf_update<<<36, 256, 0, stream>>>(input, combF, qA, qB, outp, 0);
        for (int it = 1; it < 5; ++it) {
            crf_filter_apply<<<1152, 256, 0, stream>>>(qA, qB, combF, wts);
            crf_update<<<36, 256, 0, stream>>>(input, combF, qA, qB, outp, it == 4 ? 1 : 0);
        }
    } else {
        for (int it = 0; it < 5; ++it) {
            crf_filter<<<1152, 256, 0, stream>>>(colA, qA, qB, combF);
            crf_update<<<36, 256, 0, stream>>>(input, combF, qA, qB, outp, it == 4 ? 1 : 0);
        }
    }
}

// Round 19
// 451.143 us; speedup vs baseline: 1.0088x; 1.0088x over previous
//
#include <hip/hip_runtime.h>
#include <math.h>

#define HH 96
#define WW 96
#define NN (HH*WW)
#define RAD 30
#define SQT 88   // sum over the 24 pixel-quads of Tq = ceil(maxWinX/16)

// ---- numpy's f32 SIMD exp (r13-verified): rational P5/Q2, Cody-Waite, FMA Horner,
// IEEE divide, scalef. ----
__device__ __forceinline__ float np_expf(float x) {
    float q = __builtin_rintf(x * 1.442695040888963f);
    float r = fmaf(q, -6.93145752e-1f, x);
    r = fmaf(q, -1.42860677e-6f, r);
    float num = 5.082762527590693718096e-04f;
    num = fmaf(num, r, 6.757896990527504603057e-03f);
    num = fmaf(num, r, 5.114512081637298353406e-02f);
    num = fmaf(num, r, 2.473615434895520810817e-01f);
    num = fmaf(num, r, 7.257664613233124478488e-01f);
    num = fmaf(num, r, 9.999999999980870924916e-01f);
    float den = 2.159509375685829852307e-02f;
    den = fmaf(den, r, -2.742335390411667452936e-01f);
    den = fmaf(den, r, 1.0f);
    float p = num / den;
    p = ldexpf(p, (int)q);
    if (x > 88.72283935546875f) p = __builtin_inff();
    if (x < -103.97208404541015625f) p = 0.0f;
    return p;
}

// Filter-only: x in [-42, 0] -> clamps provably dead (bit-exact on this domain).
__device__ __forceinline__ float np_expf_nc(float x) {
    float q = __builtin_rintf(x * 1.442695040888963f);
    float r = fmaf(q, -6.93145752e-1f, x);
    r = fmaf(q, -1.42860677e-6f, r);
    float num = 5.082762527590693718096e-04f;
    num = fmaf(num, r, 6.757896990527504603057e-03f);
    num = fmaf(num, r, 5.114512081637298353406e-02f);
    num = fmaf(num, r, 2.473615434895520810817e-01f);
    num = fmaf(num, r, 7.257664613233124478488e-01f);
    num = fmaf(num, r, 9.999999999980870924916e-01f);
    float den = 2.159509375685829852307e-02f;
    den = fmaf(den, r, -2.742335390411667452936e-01f);
    den = fmaf(den, r, 1.0f);
    float p = num / den;
    return ldexpf(p, (int)q);
}

// window geometry helpers
__device__ __forceinline__ int cumwin(int x) {   // sum of window widths for 0..x-1
    int g1 = (x <= 30) ? (30 * x - (x * (x - 1)) / 2) : 465;
    int g2 = (x <= 66) ? 0 : ((x - 66) * (x - 65)) / 2;
    return 61 * x - g1 - g2;
}
__device__ __forceinline__ int tq_of(int q) { return (q >= 4 && q <= 19) ? 4 : 3; }
__device__ __forceinline__ int preftq(int q) {
    return (q <= 4) ? 3 * q : ((q <= 20) ? 12 + 4 * (q - 4) : 76 + 3 * (q - 20));
}

// ---------------- prep: byte-identical to r13 ----------------
__global__ __launch_bounds__(256) void crf_prep(const float* __restrict__ input,
                                                const float* __restrict__ ref,
                                                float4* __restrict__ colA,
                                                float4* __restrict__ qA,
                                                float* __restrict__ qB) {
#pragma clang fp contract(off)
    int n = blockIdx.x * 256 + threadIdx.x;
    if (n >= NN) return;
    int py = n / WW;
    int px = n - py * WW;
    float yb = (float)py / 5.0f;
    float xb = (float)px / 5.0f;
    float r2 = ref[0 * NN + n] * 2.0f;
    float g2 = ref[1 * NN + n] * 2.0f;
    float b2 = ref[2 * NN + n] * 2.0f;
    float sqg = yb * yb + xb * xb;
    float sqb = ((sqg + r2 * r2) + g2 * g2) + b2 * b2;
    colA[n] = make_float4(r2, g2, b2, sqb);
    float l0 = input[0 * NN + n], l1 = input[1 * NN + n], l2 = input[2 * NN + n];
    float l3 = input[3 * NN + n], l4 = input[4 * NN + n];
    float m = fmaxf(fmaxf(fmaxf(fmaxf(l0, l1), l2), l3), l4);
    float e0 = np_expf(l0 - m), e1 = np_expf(l1 - m), e2 = np_expf(l2 - m);
    float e3 = np_expf(l3 - m), e4 = np_expf(l4 - m);
    float s = (((e0 + e1) + e2) + e3) + e4;
    qA[n] = make_float4(e0 / s, e1 / s, e2 / s, e3 / s);
    qB[n] = e4 / s;
}

// Common geometry (r17 mapping, center-out ordering)
#define FILTER_PREAMBLE                                                        \
    int tid = threadIdx.x;                                                     \
    int br = blockIdx.x / 12;                                                  \
    int bc = blockIdx.x - br * 12;                                             \
    int row = (br & 1) ? (48 + (br >> 1)) : (47 - (br >> 1));                  \
    int cg8 = (bc & 1) ? (6 + (bc >> 1)) : (5 - (bc >> 1));                    \
    int j = tid & 3;                                                           \
    int k = (tid >> 2) & 3;                                                    \
    int p = (tid >> 4) & 7;                                                    \
    int role = tid >> 7;                                                       \
    int py = row;                                                              \
    int px = cg8 * 8 + p;                                                      \
    int n0 = row * WW + px;                                                    \
    int ylo = py - RAD; if (ylo < 0) ylo = 0;                                  \
    int yhi = py + RAD; if (yhi > HH - 1) yhi = HH - 1;                        \
    int xlo = px - RAD; if (xlo < 0) xlo = 0;                                  \
    int xhi = px + RAD; if (xhi > WW - 1) xhi = WW - 1;                        \
    int res = k * 4 + j;                                                       \
    int cst = xlo + ((res - xlo) & 15);

// Wave-contiguous weight base: region per (row, quad, role); addr within:
// ((my-ylo)*Tq + t)*64 + lane64  -> every wave-iteration touches 256B contiguous.
#define WEIGHT_BASE                                                            \
    int qcol = cg8 * 2 + (p >> 2);                                             \
    int winY = yhi - ylo + 1;                                                  \
    int Tq = tq_of(qcol);                                                      \
    size_t wbase = (size_t)128 * ((size_t)cumwin(py) * SQT + (size_t)winY * preftq(qcol)) \
                 + (size_t)64 * role * winY * Tq;

// ---------------- filter+store: r17 compute, wave-contiguous weight writes ----------------
__global__ __launch_bounds__(256) void crf_filter_store(const float4* __restrict__ colA,
                                                        const float4* __restrict__ qA,
                                                        const float* __restrict__ qB,
                                                        float* __restrict__ combF,
                                                        float* __restrict__ wts) {
#pragma clang fp contract(off)
    __shared__ float c5[HH];
    __shared__ float sq1[HH];
    __shared__ float cg[8][5];
    if (threadIdx.x < HH) {
        float v = (float)threadIdx.x / 5.0f;
        c5[threadIdx.x] = v;
        sq1[threadIdx.x] = v * v;
    }
    __syncthreads();
    FILTER_PREAMBLE
    WEIGHT_BASE
    float* wp = wts + wbase + (tid & 63);
    float yn = c5[py], xn = c5[px];
    float sqg_n = sq1[py] + sq1[px];
    float4 cn = colA[n0];
    float sqb_n = cn.w;

    float a0 = 0.f, a1 = 0.f, a2 = 0.f, a3 = 0.f, a4 = 0.f;
    if (role == 0) {
#pragma unroll 2
        for (int my = ylo; my <= yhi; ++my) {
            float ym = c5[my];
            float tyy = yn * ym;
            int rb = my * WW;
            int ib = (my - ylo) * Tq;
            int t = 0;
            for (int mx = cst; mx <= xhi; mx += 16, ++t) {
                int m = rb + mx;
                float4 cm = colA[m];
                float4 f = qA[m];
                float fb = qB[m];
                float dot = tyy;
                dot = dot + xn * c5[mx];
                dot = dot + cn.x * cm.x;
                dot = dot + cn.y * cm.y;
                dot = dot + cn.z * cm.z;
                float d2 = (sqb_n + cm.w) - 2.0f * dot;
                d2 = fmaxf(d2, 0.0f);
                float w = np_expf_nc(-0.5f * d2);
                wp[(size_t)(ib + t) * 64] = w;
                a0 = a0 + w * f.x;
                a1 = a1 + w * f.y;
                a2 = a2 + w * f.z;
                a3 = a3 + w * f.w;
                a4 = a4 + w * fb;
            }
        }
    } else {
#pragma unroll 2
        for (int my = ylo; my <= yhi; ++my) {
            float ym = c5[my];
            float tyy = yn * ym;
            float sqy = sq1[my];
            int rb = my * WW;
            int ib = (my - ylo) * Tq;
            int t = 0;
            for (int mx = cst; mx <= xhi; mx += 16, ++t) {
                int m = rb + mx;
                float4 f = qA[m];
                float fb = qB[m];
                float dot = tyy;
                dot = dot + xn * c5[mx];
                float sqm = sqy + sq1[mx];
                float d2 = (sqg_n + sqm) - 2.0f * dot;
                d2 = fmaxf(d2, 0.0f);
                float w = np_expf_nc(-0.5f * d2);
                wp[(size_t)(ib + t) * 64] = w;
                a0 = a0 + w * f.x;
                a1 = a1 + w * f.y;
                a2 = a2 + w * f.z;
                a3 = a3 + w * f.w;
                a4 = a4 + w * fb;
            }
        }
    }
    float r_[5] = {a0, a1, a2, a3, a4};
#pragma unroll
    for (int c = 0; c < 5; ++c) {
        float v = r_[c];
        v = v + __shfl_xor(v, 4);
        v = v + __shfl_xor(v, 8);
        v = v + __shfl_xor(v, 2);
        v = v + __shfl_xor(v, 1);
        r_[c] = v;
    }
    if (role == 1 && (tid & 15) == 0) {
#pragma unroll
        for (int c = 0; c < 5; ++c) cg[p][c] = r_[c];
    }
    __syncthreads();
    if (role == 0 && (tid & 15) == 0) {
#pragma unroll
        for (int c = 0; c < 5; ++c) combF[c * NN + n0] = r_[c] + cg[p][c];
    }
}

// ---------------- filter apply: contiguous weight reads, identical chains ----------------
__global__ __launch_bounds__(256) void crf_filter_apply(const float4* __restrict__ qA,
                                                        const float* __restrict__ qB,
                                                        float* __restrict__ combF,
                                                        const float* __restrict__ wts) {
#pragma clang fp contract(off)
    __shared__ float cg[8][5];
    FILTER_PREAMBLE
    WEIGHT_BASE
    const float* wp = wts + wbase + (tid & 63);

    float a0 = 0.f, a1 = 0.f, a2 = 0.f, a3 = 0.f, a4 = 0.f;
#pragma unroll 2
    for (int my = ylo; my <= yhi; ++my) {
        int rb = my * WW;
        int ib = (my - ylo) * Tq;
        int t = 0;
        for (int mx = cst; mx <= xhi; mx += 16, ++t) {
            int m = rb + mx;
            float4 f = qA[m];
            float fb = qB[m];
            float w = wp[(size_t)(ib + t) * 64];
            a0 = a0 + w * f.x;
            a1 = a1 + w * f.y;
            a2 = a2 + w * f.z;
            a3 = a3 + w * f.w;
            a4 = a4 + w * fb;
        }
    }
    float r_[5] = {a0, a1, a2, a3, a4};
#pragma unroll
    for (int c = 0; c < 5; ++c) {
        float v = r_[c];
        v = v + __shfl_xor(v, 4);
        v = v + __shfl_xor(v, 8);
        v = v + __shfl_xor(v, 2);
        v = v + __shfl_xor(v, 1);
        r_[c] = v;
    }
    if (role == 1 && (tid & 15) == 0) {
#pragma unroll
        for (int c = 0; c < 5; ++c) cg[p][c] = r_[c];
    }
    __syncthreads();
    if (role == 0 && (tid & 15) == 0) {
#pragma unroll
        for (int c = 0; c < 5; ++c) combF[c * NN + n0] = r_[c] + cg[p][c];
    }
}

// ---------------- fallback filter: r17 verbatim ----------------
__global__ __launch_bounds__(256) void crf_filter(const float4* __restrict__ colA,
                                                  const float4* __restrict__ qA,
                                                  const float* __restrict__ qB,
                                                  float* __restrict__ combF) {
#pragma clang fp contract(off)
    __shared__ float c5[HH];
    __shared__ float sq1[HH];
    __shared__ float cg[8][5];
    if (threadIdx.x < HH) {
        float v = (float)threadIdx.x / 5.0f;
        c5[threadIdx.x] = v;
        sq1[threadIdx.x] = v * v;
    }
    __syncthreads();
    FILTER_PREAMBLE
    float yn = c5[py], xn = c5[px];
    float sqg_n = sq1[py] + sq1[px];
    float4 cn = colA[n0];
    float sqb_n = cn.w;

    float a0 = 0.f, a1 = 0.f, a2 = 0.f, a3 = 0.f, a4 = 0.f;
    if (role == 0) {
#pragma unroll 2
        for (int my = ylo; my <= yhi; ++my) {
            float ym = c5[my];
            float tyy = yn * ym;
            int rb = my * WW;
            for (int mx = cst; mx <= xhi; mx += 16) {
                int m = rb + mx;
                float4 cm = colA[m];
                float4 f = qA[m];
                float fb = qB[m];
                float dot = tyy;
                dot = dot + xn * c5[mx];
                dot = dot + cn.x * cm.x;
                dot = dot + cn.y * cm.y;
                dot = dot + cn.z * cm.z;
                float d2 = (sqb_n + cm.w) - 2.0f * dot;
                d2 = fmaxf(d2, 0.0f);
                float w = np_expf_nc(-0.5f * d2);
                a0 = a0 + w * f.x;
                a1 = a1 + w * f.y;
                a2 = a2 + w * f.z;
                a3 = a3 + w * f.w;
                a4 = a4 + w * fb;
            }
        }
    } else {
#pragma unroll 2
        for (int my = ylo; my <= yhi; ++my) {
            float ym = c5[my];
            float tyy = yn * ym;
            float sqy = sq1[my];
            int rb = my * WW;
            for (int mx = cst; mx <= xhi; mx += 16) {
                int m = rb + mx;
                float4 f = qA[m];
                float fb = qB[m];
                float dot = tyy;
                dot = dot + xn * c5[mx];
                float sqm = sqy + sq1[mx];
                float d2 = (sqg_n + sqm) - 2.0f * dot;
                d2 = fmaxf(d2, 0.0f);
                float w = np_expf_nc(-0.5f * d2);
                a0 = a0 + w * f.x;
                a1 = a1 + w * f.y;
                a2 = a2 + w * f.z;
                a3 = a3 + w * f.w;
                a4 = a4 + w * fb;
            }
        }
    }
    float r_[5] = {a0, a1, a2, a3, a4};
#pragma unroll
    for (int c = 0; c < 5; ++c) {
        float v = r_[c];
        v = v + __shfl_xor(v, 4);
        v = v + __shfl_xor(v, 8);
        v = v + __shfl_xor(v, 2);
        v = v + __shfl_xor(v, 1);
        r_[c] = v;
    }
    if (role == 1 && (tid & 15) == 0) {
#pragma unroll
        for (int c = 0; c < 5; ++c) cg[p][c] = r_[c];
    }
    __syncthreads();
    if (role == 0 && (tid & 15) == 0) {
#pragma unroll
        for (int c = 0; c < 5; ++c) combF[c * NN + n0] = r_[c] + cg[p][c];
    }
}

// ---------------- update: byte-identical to r13 ----------------
__global__ __launch_bounds__(256) void crf_update(const float* __restrict__ input,
                                                  const float* __restrict__ combF,
                                                  float4* __restrict__ qA,
                                                  float* __restrict__ qB,
                                                  float* __restrict__ outp,
                                                  int writeOut) {
#pragma clang fp contract(off)
    int n = blockIdx.x * 256 + threadIdx.x;
    if (n >= NN) return;
    int py = n / WW;
    int px = n - py * WW;
    float v[3][3][5];
#pragma unroll
    for (int ky = 0; ky < 3; ++ky) {
        int yy = py + ky - 1; yy = yy < 0 ? 0 : (yy > HH - 1 ? HH - 1 : yy);
#pragma unroll
        for (int kx = 0; kx < 3; ++kx) {
            int xx = px + kx - 1; xx = xx < 0 ? 0 : (xx > WW - 1 ? WW - 1 : xx);
            int m = yy * WW + xx;
#pragma unroll
            for (int c = 0; c < 5; ++c) v[ky][kx][c] = combF[c * NN + m];
        }
    }
    float l[5];
#pragma unroll
    for (int o = 0; o < 5; ++o) {
        float u = 0.f;
#pragma unroll
        for (int ky = 0; ky < 3; ++ky) {
#pragma unroll
            for (int kx = 0; kx < 3; ++kx) {
                float t = 0.f;
#pragma unroll
                for (int ci = 0; ci < 5; ++ci)
                    if (ci != o) t = t + v[ky][kx][ci];
                u = u + t;
            }
        }
        l[o] = input[o * NN + n] - 3.0f * u;
    }
    float m = fmaxf(fmaxf(fmaxf(fmaxf(l[0], l[1]), l[2]), l[3]), l[4]);
    float e0 = np_expf(l[0] - m), e1 = np_expf(l[1] - m), e2 = np_expf(l[2] - m);
    float e3 = np_expf(l[3] - m), e4 = np_expf(l[4] - m);
    float s = (((e0 + e1) + e2) + e3) + e4;
    float o0 = e0 / s, o1 = e1 / s, o2 = e2 / s, o3 = e3 / s, o4 = e4 / s;
    qA[n] = make_float4(o0, o1, o2, o3);
    qB[n] = o4;
    if (writeOut) {
        outp[0 * NN + n] = o0;
        outp[1 * NN + n] = o1;
        outp[2 * NN + n] = o2;
        outp[3 * NN + n] = o3;
        outp[4 * NN + n] = o4;
    }
}

extern "C" void kernel_launch(void* const* d_in, const int* in_sizes, int n_in,
                              void* d_out, int out_size, void* d_ws, size_t ws_size,
                              hipStream_t stream) {
    const float* input = (const float*)d_in[0];   // [1,5,96,96] f32
    const float* ref = (const float*)d_in[1];     // [1,3,96,96] f32
    float* ws = (float*)d_ws;
    float4* colA = (float4*)(ws + 0 * NN);        // 4*NN
    float4* qA = (float4*)(ws + 4 * NN);          // 4*NN
    float* qB = ws + 8 * NN;                      // NN
    float* combF = ws + 9 * NN;                   // 5*NN
    float* wts = ws + 14 * NN;                    // 128 * 4926 * 88 floats (~222MB)
    float* outp = (float*)d_out;

    size_t wfloats = (size_t)128 * 4926 * SQT;    // 55,486,464
    size_t need = ((size_t)14 * NN + wfloats) * sizeof(float);
    crf_prep<<<36, 256, 0, stream>>>(input, ref, colA, qA, qB);
    if (ws_size >= need) {
        crf_filter_store<<<1152, 256, 0, stream>>>(colA, qA, qB, combF, wts);
        crf_update<<<36, 256, 0, stream>>>(input, combF, qA, qB, outp, 0);
        for (int it = 1; it < 5; ++it) {
            crf_filter_apply<<<1152, 256, 0, stream>>>(qA, qB, combF, wts);
            crf_update<<<36, 256, 0, stream>>>(input, combF, qA, qB, outp, it == 4 ? 1 : 0);
        }
    } else {
        for (int it = 0; it < 5; ++it) {
            crf_filter<<<1152, 256, 0, stream>>>(colA, qA, qB, combF);
            crf_update<<<36, 256, 0, stream>>>(input, combF, qA, qB, outp, it == 4 ? 1 : 0);
        }
    }
}

// Round 20
// 440.946 us; speedup vs baseline: 1.0322x; 1.0231x over previous
//
#include <hip/hip_runtime.h>
#include <math.h>

#define HH 96
#define WW 96
#define NN (HH*WW)
#define RAD 30
#define SQT 88   // sum over the 24 pixel-quads of Tq

// ---- numpy's f32 SIMD exp (r13-verified) ----
__device__ __forceinline__ float np_expf(float x) {
    float q = __builtin_rintf(x * 1.442695040888963f);
    float r = fmaf(q, -6.93145752e-1f, x);
    r = fmaf(q, -1.42860677e-6f, r);
    float num = 5.082762527590693718096e-04f;
    num = fmaf(num, r, 6.757896990527504603057e-03f);
    num = fmaf(num, r, 5.114512081637298353406e-02f);
    num = fmaf(num, r, 2.473615434895520810817e-01f);
    num = fmaf(num, r, 7.257664613233124478488e-01f);
    num = fmaf(num, r, 9.999999999980870924916e-01f);
    float den = 2.159509375685829852307e-02f;
    den = fmaf(den, r, -2.742335390411667452936e-01f);
    den = fmaf(den, r, 1.0f);
    float p = num / den;
    p = ldexpf(p, (int)q);
    if (x > 88.72283935546875f) p = __builtin_inff();
    if (x < -103.97208404541015625f) p = 0.0f;
    return p;
}

// Filter-only: x in [-42, 0] -> clamps provably dead (bit-exact on this domain).
__device__ __forceinline__ float np_expf_nc(float x) {
    float q = __builtin_rintf(x * 1.442695040888963f);
    float r = fmaf(q, -6.93145752e-1f, x);
    r = fmaf(q, -1.42860677e-6f, r);
    float num = 5.082762527590693718096e-04f;
    num = fmaf(num, r, 6.757896990527504603057e-03f);
    num = fmaf(num, r, 5.114512081637298353406e-02f);
    num = fmaf(num, r, 2.473615434895520810817e-01f);
    num = fmaf(num, r, 7.257664613233124478488e-01f);
    num = fmaf(num, r, 9.999999999980870924916e-01f);
    float den = 2.159509375685829852307e-02f;
    den = fmaf(den, r, -2.742335390411667452936e-01f);
    den = fmaf(den, r, 1.0f);
    float p = num / den;
    return ldexpf(p, (int)q);
}

// window geometry helpers
__device__ __forceinline__ int cumwin(int x) {
    int g1 = (x <= 30) ? (30 * x - (x * (x - 1)) / 2) : 465;
    int g2 = (x <= 66) ? 0 : ((x - 66) * (x - 65)) / 2;
    return 61 * x - g1 - g2;
}
__device__ __forceinline__ int tq_of(int q) { return (q >= 4 && q <= 19) ? 4 : 3; }
__device__ __forceinline__ int preftq(int q) {
    return (q <= 4) ? 3 * q : ((q <= 20) ? 12 + 4 * (q - 4) : 76 + 3 * (q - 20));
}

// ---------------- prep: byte-identical to r13 ----------------
__global__ __launch_bounds__(256) void crf_prep(const float* __restrict__ input,
                                                const float* __restrict__ ref,
                                                float4* __restrict__ colA,
                                                float4* __restrict__ qA,
                                                float* __restrict__ qB) {
#pragma clang fp contract(off)
    int n = blockIdx.x * 256 + threadIdx.x;
    if (n >= NN) return;
    int py = n / WW;
    int px = n - py * WW;
    float yb = (float)py / 5.0f;
    float xb = (float)px / 5.0f;
    float r2 = ref[0 * NN + n] * 2.0f;
    float g2 = ref[1 * NN + n] * 2.0f;
    float b2 = ref[2 * NN + n] * 2.0f;
    float sqg = yb * yb + xb * xb;
    float sqb = ((sqg + r2 * r2) + g2 * g2) + b2 * b2;
    colA[n] = make_float4(r2, g2, b2, sqb);
    float l0 = input[0 * NN + n], l1 = input[1 * NN + n], l2 = input[2 * NN + n];
    float l3 = input[3 * NN + n], l4 = input[4 * NN + n];
    float m = fmaxf(fmaxf(fmaxf(fmaxf(l0, l1), l2), l3), l4);
    float e0 = np_expf(l0 - m), e1 = np_expf(l1 - m), e2 = np_expf(l2 - m);
    float e3 = np_expf(l3 - m), e4 = np_expf(l4 - m);
    float s = (((e0 + e1) + e2) + e3) + e4;
    qA[n] = make_float4(e0 / s, e1 / s, e2 / s, e3 / s);
    qB[n] = e4 / s;
}

// Common geometry (r17 mapping, center-out ordering)
#define FILTER_PREAMBLE                                                        \
    int tid = threadIdx.x;                                                     \
    int br = blockIdx.x / 12;                                                  \
    int bc = blockIdx.x - br * 12;                                             \
    int row = (br & 1) ? (48 + (br >> 1)) : (47 - (br >> 1));                  \
    int cg8 = (bc & 1) ? (6 + (bc >> 1)) : (5 - (bc >> 1));                    \
    int j = tid & 3;                                                           \
    int k = (tid >> 2) & 3;                                                    \
    int p = (tid >> 4) & 7;                                                    \
    int role = tid >> 7;                                                       \
    int py = row;                                                              \
    int px = cg8 * 8 + p;                                                      \
    int n0 = row * WW + px;                                                    \
    int ylo = py - RAD; if (ylo < 0) ylo = 0;                                  \
    int yhi = py + RAD; if (yhi > HH - 1) yhi = HH - 1;                        \
    int xlo = px - RAD; if (xlo < 0) xlo = 0;                                  \
    int xhi = px + RAD; if (xhi > WW - 1) xhi = WW - 1;                        \
    int res = k * 4 + j;                                                       \
    int cst = xlo + ((res - xlo) & 15);

// Bilateral-only wave-contiguous weight base: region per (row, quad);
// addr = wbase + ((my-ylo)*Tq + t)*64 + (tid&63) -> 256B contiguous per wave-step.
#define WEIGHT_BASE                                                            \
    int qcol = cg8 * 2 + (p >> 2);                                             \
    int winY = yhi - ylo + 1;                                                  \
    int Tq = tq_of(qcol);                                                      \
    size_t wbase = (size_t)64 * ((size_t)cumwin(py) * SQT + (size_t)winY * preftq(qcol));

// ---------------- filter+store: r17 compute, stores BILATERAL weights only ----------------
__global__ __launch_bounds__(256) void crf_filter_store(const float4* __restrict__ colA,
                                                        const float4* __restrict__ qA,
                                                        const float* __restrict__ qB,
                                                        float* __restrict__ combF,
                                                        float* __restrict__ wts) {
#pragma clang fp contract(off)
    __shared__ float c5[HH];
    __shared__ float sq1[HH];
    __shared__ float cg[8][5];
    if (threadIdx.x < HH) {
        float v = (float)threadIdx.x / 5.0f;
        c5[threadIdx.x] = v;
        sq1[threadIdx.x] = v * v;
    }
    __syncthreads();
    FILTER_PREAMBLE
    WEIGHT_BASE
    float* wp = wts + wbase + (tid & 63);
    float yn = c5[py], xn = c5[px];
    float sqg_n = sq1[py] + sq1[px];
    float4 cn = colA[n0];
    float sqb_n = cn.w;

    float a0 = 0.f, a1 = 0.f, a2 = 0.f, a3 = 0.f, a4 = 0.f;
    if (role == 0) {
#pragma unroll 2
        for (int my = ylo; my <= yhi; ++my) {
            float ym = c5[my];
            float tyy = yn * ym;
            int rb = my * WW;
            int ib = (my - ylo) * Tq;
            int t = 0;
            for (int mx = cst; mx <= xhi; mx += 16, ++t) {
                int m = rb + mx;
                float4 cm = colA[m];
                float4 f = qA[m];
                float fb = qB[m];
                float dot = tyy;
                dot = dot + xn * c5[mx];
                dot = dot + cn.x * cm.x;
                dot = dot + cn.y * cm.y;
                dot = dot + cn.z * cm.z;
                float d2 = (sqb_n + cm.w) - 2.0f * dot;
                d2 = fmaxf(d2, 0.0f);
                float w = np_expf_nc(-0.5f * d2);
                wp[(size_t)(ib + t) * 64] = w;
                a0 = a0 + w * f.x;
                a1 = a1 + w * f.y;
                a2 = a2 + w * f.z;
                a3 = a3 + w * f.w;
                a4 = a4 + w * fb;
            }
        }
    } else {
#pragma unroll 2
        for (int my = ylo; my <= yhi; ++my) {
            float ym = c5[my];
            float tyy = yn * ym;
            float sqy = sq1[my];
            int rb = my * WW;
            for (int mx = cst; mx <= xhi; mx += 16) {
                int m = rb + mx;
                float4 f = qA[m];
                float fb = qB[m];
                float dot = tyy;
                dot = dot + xn * c5[mx];
                float sqm = sqy + sq1[mx];
                float d2 = (sqg_n + sqm) - 2.0f * dot;
                d2 = fmaxf(d2, 0.0f);
                float w = np_expf_nc(-0.5f * d2);
                a0 = a0 + w * f.x;
                a1 = a1 + w * f.y;
                a2 = a2 + w * f.z;
                a3 = a3 + w * f.w;
                a4 = a4 + w * fb;
            }
        }
    }
    float r_[5] = {a0, a1, a2, a3, a4};
#pragma unroll
    for (int c = 0; c < 5; ++c) {
        float v = r_[c];
        v = v + __shfl_xor(v, 4);
        v = v + __shfl_xor(v, 8);
        v = v + __shfl_xor(v, 2);
        v = v + __shfl_xor(v, 1);
        r_[c] = v;
    }
    if (role == 1 && (tid & 15) == 0) {
#pragma unroll
        for (int c = 0; c < 5; ++c) cg[p][c] = r_[c];
    }
    __syncthreads();
    if (role == 0 && (tid & 15) == 0) {
#pragma unroll
        for (int c = 0; c < 5; ++c) combF[c * NN + n0] = r_[c] + cg[p][c];
    }
}

// ---------------- filter apply: bil waves load cached weights, gauss waves recompute ----------------
__global__ __launch_bounds__(256) void crf_filter_apply(const float4* __restrict__ qA,
                                                        const float* __restrict__ qB,
                                                        float* __restrict__ combF,
                                                        const float* __restrict__ wts) {
#pragma clang fp contract(off)
    __shared__ float c5[HH];
    __shared__ float sq1[HH];
    __shared__ float cg[8][5];
    if (threadIdx.x < HH) {
        float v = (float)threadIdx.x / 5.0f;
        c5[threadIdx.x] = v;
        sq1[threadIdx.x] = v * v;
    }
    __syncthreads();
    FILTER_PREAMBLE
    WEIGHT_BASE

    float a0 = 0.f, a1 = 0.f, a2 = 0.f, a3 = 0.f, a4 = 0.f;
    if (role == 0) {
        const float* wp = wts + wbase + (tid & 63);
#pragma unroll 2
        for (int my = ylo; my <= yhi; ++my) {
            int rb = my * WW;
            int ib = (my - ylo) * Tq;
            int t = 0;
            for (int mx = cst; mx <= xhi; mx += 16, ++t) {
                int m = rb + mx;
                float4 f = qA[m];
                float fb = qB[m];
                float w = wp[(size_t)(ib + t) * 64];
                a0 = a0 + w * f.x;
                a1 = a1 + w * f.y;
                a2 = a2 + w * f.z;
                a3 = a3 + w * f.w;
                a4 = a4 + w * fb;
            }
        }
    } else {
        float yn = c5[py], xn = c5[px];
        float sqg_n = sq1[py] + sq1[px];
#pragma unroll 2
        for (int my = ylo; my <= yhi; ++my) {
            float ym = c5[my];
            float tyy = yn * ym;
            float sqy = sq1[my];
            int rb = my * WW;
            for (int mx = cst; mx <= xhi; mx += 16) {
                int m = rb + mx;
                float4 f = qA[m];
                float fb = qB[m];
                float dot = tyy;
                dot = dot + xn * c5[mx];
                float sqm = sqy + sq1[mx];
                float d2 = (sqg_n + sqm) - 2.0f * dot;
                d2 = fmaxf(d2, 0.0f);
                float w = np_expf_nc(-0.5f * d2);
                a0 = a0 + w * f.x;
                a1 = a1 + w * f.y;
                a2 = a2 + w * f.z;
                a3 = a3 + w * f.w;
                a4 = a4 + w * fb;
            }
        }
    }
    float r_[5] = {a0, a1, a2, a3, a4};
#pragma unroll
    for (int c = 0; c < 5; ++c) {
        float v = r_[c];
        v = v + __shfl_xor(v, 4);
        v = v + __shfl_xor(v, 8);
        v = v + __shfl_xor(v, 2);
        v = v + __shfl_xor(v, 1);
        r_[c] = v;
    }
    if (role == 1 && (tid & 15) == 0) {
#pragma unroll
        for (int c = 0; c < 5; ++c) cg[p][c] = r_[c];
    }
    __syncthreads();
    if (role == 0 && (tid & 15) == 0) {
#pragma unroll
        for (int c = 0; c < 5; ++c) combF[c * NN + n0] = r_[c] + cg[p][c];
    }
}

// ---------------- fallback filter: r17 verbatim ----------------
__global__ __launch_bounds__(256) void crf_filter(const float4* __restrict__ colA,
                                                  const float4* __restrict__ qA,
                                                  const float* __restrict__ qB,
                                                  float* __restrict__ combF) {
#pragma clang fp contract(off)
    __shared__ float c5[HH];
    __shared__ float sq1[HH];
    __shared__ float cg[8][5];
    if (threadIdx.x < HH) {
        float v = (float)threadIdx.x / 5.0f;
        c5[threadIdx.x] = v;
        sq1[threadIdx.x] = v * v;
    }
    __syncthreads();
    FILTER_PREAMBLE
    float yn = c5[py], xn = c5[px];
    float sqg_n = sq1[py] + sq1[px];
    float4 cn = colA[n0];
    float sqb_n = cn.w;

    float a0 = 0.f, a1 = 0.f, a2 = 0.f, a3 = 0.f, a4 = 0.f;
    if (role == 0) {
#pragma unroll 2
        for (int my = ylo; my <= yhi; ++my) {
            float ym = c5[my];
            float tyy = yn * ym;
            int rb = my * WW;
            for (int mx = cst; mx <= xhi; mx += 16) {
                int m = rb + mx;
                float4 cm = colA[m];
                float4 f = qA[m];
                float fb = qB[m];
                float dot = tyy;
                dot = dot + xn * c5[mx];
                dot = dot + cn.x * cm.x;
                dot = dot + cn.y * cm.y;
                dot = dot + cn.z * cm.z;
                float d2 = (sqb_n + cm.w) - 2.0f * dot;
                d2 = fmaxf(d2, 0.0f);
                float w = np_expf_nc(-0.5f * d2);
                a0 = a0 + w * f.x;
                a1 = a1 + w * f.y;
                a2 = a2 + w * f.z;
                a3 = a3 + w * f.w;
                a4 = a4 + w * fb;
            }
        }
    } else {
#pragma unroll 2
        for (int my = ylo; my <= yhi; ++my) {
            float ym = c5[my];
            float tyy = yn * ym;
            float sqy = sq1[my];
            int rb = my * WW;
            for (int mx = cst; mx <= xhi; mx += 16) {
                int m = rb + mx;
                float4 f = qA[m];
                float fb = qB[m];
                float dot = tyy;
                dot = dot + xn * c5[mx];
                float sqm = sqy + sq1[mx];
                float d2 = (sqg_n + sqm) - 2.0f * dot;
                d2 = fmaxf(d2, 0.0f);
                float w = np_expf_nc(-0.5f * d2);
                a0 = a0 + w * f.x;
                a1 = a1 + w * f.y;
                a2 = a2 + w * f.z;
                a3 = a3 + w * f.w;
                a4 = a4 + w * fb;
            }
        }
    }
    float r_[5] = {a0, a1, a2, a3, a4};
#pragma unroll
    for (int c = 0; c < 5; ++c) {
        float v = r_[c];
        v = v + __shfl_xor(v, 4);
        v = v + __shfl_xor(v, 8);
        v = v + __shfl_xor(v, 2);
        v = v + __shfl_xor(v, 1);
        r_[c] = v;
    }
    if (role == 1 && (tid & 15) == 0) {
#pragma unroll
        for (int c = 0; c < 5; ++c) cg[p][c] = r_[c];
    }
    __syncthreads();
    if (role == 0 && (tid & 15) == 0) {
#pragma unroll
        for (int c = 0; c < 5; ++c) combF[c * NN + n0] = r_[c] + cg[p][c];
    }
}

// ---------------- update: byte-identical to r13 ----------------
__global__ __launch_bounds__(256) void crf_update(const float* __restrict__ input,
                                                  const float* __restrict__ combF,
                                                  float4* __restrict__ qA,
                                                  float* __restrict__ qB,
                                                  float* __restrict__ outp,
                                                  int writeOut) {
#pragma clang fp contract(off)
    int n = blockIdx.x * 256 + threadIdx.x;
    if (n >= NN) return;
    int py = n / WW;
    int px = n - py * WW;
    float v[3][3][5];
#pragma unroll
    for (int ky = 0; ky < 3; ++ky) {
        int yy = py + ky - 1; yy = yy < 0 ? 0 : (yy > HH - 1 ? HH - 1 : yy);
#pragma unroll
        for (int kx = 0; kx < 3; ++kx) {
            int xx = px + kx - 1; xx = xx < 0 ? 0 : (xx > WW - 1 ? WW - 1 : xx);
            int m = yy * WW + xx;
#pragma unroll
            for (int c = 0; c < 5; ++c) v[ky][kx][c] = combF[c * NN + m];
        }
    }
    float l[5];
#pragma unroll
    for (int o = 0; o < 5; ++o) {
        float u = 0.f;
#pragma unroll
        for (int ky = 0; ky < 3; ++ky) {
#pragma unroll
            for (int kx = 0; kx < 3; ++kx) {
                float t = 0.f;
#pragma unroll
                for (int ci = 0; ci < 5; ++ci)
                    if (ci != o) t = t + v[ky][kx][ci];
                u = u + t;
            }
        }
        l[o] = input[o * NN + n] - 3.0f * u;
    }
    float m = fmaxf(fmaxf(fmaxf(fmaxf(l[0], l[1]), l[2]), l[3]), l[4]);
    float e0 = np_expf(l[0] - m), e1 = np_expf(l[1] - m), e2 = np_expf(l[2] - m);
    float e3 = np_expf(l[3] - m), e4 = np_expf(l[4] - m);
    float s = (((e0 + e1) + e2) + e3) + e4;
    float o0 = e0 / s, o1 = e1 / s, o2 = e2 / s, o3 = e3 / s, o4 = e4 / s;
    qA[n] = make_float4(o0, o1, o2, o3);
    qB[n] = o4;
    if (writeOut) {
        outp[0 * NN + n] = o0;
        outp[1 * NN + n] = o1;
        outp[2 * NN + n] = o2;
        outp[3 * NN + n] = o3;
        outp[4 * NN + n] = o4;
    }
}

extern "C" void kernel_launch(void* const* d_in, const int* in_sizes, int n_in,
                              void* d_out, int out_size, void* d_ws, size_t ws_size,
                              hipStream_t stream) {
    const float* input = (const float*)d_in[0];   // [1,5,96,96] f32
    const float* ref = (const float*)d_in[1];     // [1,3,96,96] f32
    float* ws = (float*)d_ws;
    float4* colA = (float4*)(ws + 0 * NN);        // 4*NN
    float4* qA = (float4*)(ws + 4 * NN);          // 4*NN
    float* qB = ws + 8 * NN;                      // NN
    float* combF = ws + 9 * NN;                   // 5*NN
    float* wts = ws + 14 * NN;                    // 64 * 4926 * 88 floats (~111MB)
    float* outp = (float*)d_out;

    size_t wfloats = (size_t)64 * 4926 * SQT;     // 27,743,232
    size_t need = ((size_t)14 * NN + wfloats) * sizeof(float);
    crf_prep<<<36, 256, 0, stream>>>(input, ref, colA, qA, qB);
    if (ws_size >= need) {
        crf_filter_store<<<1152, 256, 0, stream>>>(colA, qA, qB, combF, wts);
        crf_update<<<36, 256, 0, stream>>>(input, combF, qA, qB, outp, 0);
        for (int it = 1; it < 5; ++it) {
            crf_filter_apply<<<1152, 256, 0, stream>>>(qA, qB, combF, wts);
            crf_update<<<36, 256, 0, stream>>>(input, combF, qA, qB, outp, it == 4 ? 1 : 0);
        }
    } else {
        for (int it = 0; it < 5; ++it) {
            crf_filter<<<1152, 256, 0, stream>>>(colA, qA, qB, combF);
            crf_update<<<36, 256, 0, stream>>>(input, combF, qA, qB, outp, it == 4 ? 1 : 0);
        }
    }
}

// Round 21
// 386.705 us; speedup vs baseline: 1.1769x; 1.1403x over previous
//
#include <hip/hip_runtime.h>
#include <math.h>

#define HH 96
#define WW 96
#define NN (HH*WW)
#define RAD 30

// ---- numpy's f32 SIMD exp (r13-verified): rational P5/Q2, Cody-Waite, FMA Horner,
// IEEE divide, scalef. ----
__device__ __forceinline__ float np_expf(float x) {
    float q = __builtin_rintf(x * 1.442695040888963f);
    float r = fmaf(q, -6.93145752e-1f, x);
    r = fmaf(q, -1.42860677e-6f, r);
    float num = 5.082762527590693718096e-04f;
    num = fmaf(num, r, 6.757896990527504603057e-03f);
    num = fmaf(num, r, 5.114512081637298353406e-02f);
    num = fmaf(num, r, 2.473615434895520810817e-01f);
    num = fmaf(num, r, 7.257664613233124478488e-01f);
    num = fmaf(num, r, 9.999999999980870924916e-01f);
    float den = 2.159509375685829852307e-02f;
    den = fmaf(den, r, -2.742335390411667452936e-01f);
    den = fmaf(den, r, 1.0f);
    float p = num / den;
    p = ldexpf(p, (int)q);
    if (x > 88.72283935546875f) p = __builtin_inff();
    if (x < -103.97208404541015625f) p = 0.0f;
    return p;
}

// Filter-only: x = -0.5*d2, d2 in [0, ~84] -> x in [-42, 0]:
// range clamps provably never taken -> removed (bit-exact on this domain).
__device__ __forceinline__ float np_expf_nc(float x) {
    float q = __builtin_rintf(x * 1.442695040888963f);
    float r = fmaf(q, -6.93145752e-1f, x);
    r = fmaf(q, -1.42860677e-6f, r);
    float num = 5.082762527590693718096e-04f;
    num = fmaf(num, r, 6.757896990527504603057e-03f);
    num = fmaf(num, r, 5.114512081637298353406e-02f);
    num = fmaf(num, r, 2.473615434895520810817e-01f);
    num = fmaf(num, r, 7.257664613233124478488e-01f);
    num = fmaf(num, r, 9.999999999980870924916e-01f);
    float den = 2.159509375685829852307e-02f;
    den = fmaf(den, r, -2.742335390411667452936e-01f);
    den = fmaf(den, r, 1.0f);
    float p = num / den;
    return ldexpf(p, (int)q);
}

// ---------------- prep: byte-identical to r13 ----------------
__global__ __launch_bounds__(256) void crf_prep(const float* __restrict__ input,
                                                const float* __restrict__ ref,
                                                float4* __restrict__ colA,
                                                float4* __restrict__ qA,
                                                float* __restrict__ qB) {
#pragma clang fp contract(off)
    int n = blockIdx.x * 256 + threadIdx.x;
    if (n >= NN) return;
    int py = n / WW;
    int px = n - py * WW;
    float yb = (float)py / 5.0f;
    float xb = (float)px / 5.0f;
    float r2 = ref[0 * NN + n] * 2.0f;
    float g2 = ref[1 * NN + n] * 2.0f;
    float b2 = ref[2 * NN + n] * 2.0f;
    float sqg = yb * yb + xb * xb;
    float sqb = ((sqg + r2 * r2) + g2 * g2) + b2 * b2;
    colA[n] = make_float4(r2, g2, b2, sqb);
    float l0 = input[0 * NN + n], l1 = input[1 * NN + n], l2 = input[2 * NN + n];
    float l3 = input[3 * NN + n], l4 = input[4 * NN + n];
    float m = fmaxf(fmaxf(fmaxf(fmaxf(l0, l1), l2), l3), l4);
    float e0 = np_expf(l0 - m), e1 = np_expf(l1 - m), e2 = np_expf(l2 - m);
    float e3 = np_expf(l3 - m), e4 = np_expf(l4 - m);
    float s = (((e0 + e1) + e2) + e3) + e4;
    qA[n] = make_float4(e0 / s, e1 / s, e2 / s, e3 / s);
    qB[n] = e4 / s;
}

// ---------------- filter: r17 structure, per-lane column constants hoisted ----------------
// Block = 256 threads = 4 waves, 8 consecutive pixels. Wave role = tid>>7 (waves 0-1
// bilateral, 2-3 gaussian). 16 lanes/pixel (k = bits 2-3, j = bits 0-1) cover
// mx % 16 == 4k+j ascending, my ascending — r13's exact sub-chains. Each lane's <=4
// columns are fixed: c5[mx_t], sq1[mx_t] hoisted to registers (same values, same ops
// -> bit-exact). Reduce xor4,8 then xor2,1; gauss totals via LDS; bil lane writes
// fl(bil + gauss). Center-out block ordering (heavy windows first).
__global__ __launch_bounds__(256) void crf_filter(const float4* __restrict__ colA,
                                                  const float4* __restrict__ qA,
                                                  const float* __restrict__ qB,
                                                  float* __restrict__ combF) {
#pragma clang fp contract(off)
    __shared__ float c5[HH];     // fl(i/5)
    __shared__ float sq1[HH];    // fl(c5^2)
    __shared__ float cg[8][5];   // gaussian totals per pixel
    int tid = threadIdx.x;
    if (tid < HH) {
        float v = (float)tid / 5.0f;
        c5[tid] = v;
        sq1[tid] = v * v;
    }
    __syncthreads();

    int br = blockIdx.x / 12;
    int bc = blockIdx.x - br * 12;
    int row = (br & 1) ? (48 + (br >> 1)) : (47 - (br >> 1));
    int cg8 = (bc & 1) ? (6 + (bc >> 1)) : (5 - (bc >> 1));

    int j = tid & 3;                  // SSE column lane
    int k = (tid >> 2) & 3;           // mx-bin
    int p = (tid >> 4) & 7;           // pixel within block (0..7)
    int role = tid >> 7;              // 0 = bilateral (waves 0-1), 1 = gaussian (2-3)
    int py = row;
    int px = cg8 * 8 + p;
    int n0 = row * WW + px;
    float yn = c5[py], xn = c5[px];
    float sqg_n = sq1[py] + sq1[px];
    float4 cn = colA[n0];             // (r,g,b,sqb)
    float sqb_n = cn.w;
    int ylo = py - RAD; if (ylo < 0) ylo = 0;
    int yhi = py + RAD; if (yhi > HH - 1) yhi = HH - 1;
    int xlo = px - RAD; if (xlo < 0) xlo = 0;
    int xhi = px + RAD; if (xhi > WW - 1) xhi = WW - 1;
    int res = k * 4 + j;                       // mx residue mod 16
    int cst = xlo + ((res - xlo) & 15);        // first col >= xlo with mx%16 == res

    // hoist the lane's (<=4) column constants into registers (bit-identical values)
    int T = (xhi - cst) / 16 + 1;              // 1..4 columns for this lane
    int mx0 = cst, mx1 = cst + 16, mx2 = cst + 32, mx3 = cst + 48;
    int i1 = mx1 > 95 ? 95 : mx1;
    int i2 = mx2 > 95 ? 95 : mx2;
    int i3 = mx3 > 95 ? 95 : mx3;
    float cx0 = c5[mx0], cx1 = c5[i1], cx2 = c5[i2], cx3 = c5[i3];
    float sx0 = sq1[mx0], sx1 = sq1[i1], sx2 = sq1[i2], sx3 = sq1[i3];

    float a0 = 0.f, a1 = 0.f, a2 = 0.f, a3 = 0.f, a4 = 0.f;
    if (role == 0) {                  // wave-uniform branch: no divergence
#define BIL_BODY(MX, CX)                                                       \
        {                                                                      \
            int m = rb + (MX);                                                 \
            float4 cm = colA[m];                                               \
            float4 f = qA[m];                                                  \
            float fb = qB[m];                                                  \
            float dot = tyy;                                                   \
            dot = dot + xn * (CX);                                             \
            dot = dot + cn.x * cm.x;                                           \
            dot = dot + cn.y * cm.y;                                           \
            dot = dot + cn.z * cm.z;                                           \
            float d2 = (sqb_n + cm.w) - 2.0f * dot;                            \
            d2 = fmaxf(d2, 0.0f);                                              \
            float w = np_expf_nc(-0.5f * d2);                                  \
            a0 = a0 + w * f.x;                                                 \
            a1 = a1 + w * f.y;                                                 \
            a2 = a2 + w * f.z;                                                 \
            a3 = a3 + w * f.w;                                                 \
            a4 = a4 + w * fb;                                                  \
        }
#pragma unroll 2
        for (int my = ylo; my <= yhi; ++my) {
            float ym = c5[my];
            float tyy = yn * ym;
            int rb = my * WW;
            BIL_BODY(mx0, cx0)                       // t = 0 always valid
            if (T > 1) BIL_BODY(mx1, cx1)
            if (T > 2) BIL_BODY(mx2, cx2)
            if (T > 3) BIL_BODY(mx3, cx3)
        }
#undef BIL_BODY
    } else {
#define GAU_BODY(MX, CX, SX)                                                   \
        {                                                                      \
            int m = rb + (MX);                                                 \
            float4 f = qA[m];                                                  \
            float fb = qB[m];                                                  \
            float dot = tyy;                                                   \
            dot = dot + xn * (CX);                                             \
            float sqm = sqy + (SX);                                            \
            float d2 = (sqg_n + sqm) - 2.0f * dot;                             \
            d2 = fmaxf(d2, 0.0f);                                              \
            float w = np_expf_nc(-0.5f * d2);                                  \
            a0 = a0 + w * f.x;                                                 \
            a1 = a1 + w * f.y;                                                 \
            a2 = a2 + w * f.z;                                                 \
            a3 = a3 + w * f.w;                                                 \
            a4 = a4 + w * fb;                                                  \
        }
#pragma unroll 2
        for (int my = ylo; my <= yhi; ++my) {
            float ym = c5[my];
            float tyy = yn * ym;
            float sqy = sq1[my];
            int rb = my * WW;
            GAU_BODY(mx0, cx0, sx0)
            if (T > 1) GAU_BODY(mx1, cx1, sx1)
            if (T > 2) GAU_BODY(mx2, cx2, sx2)
            if (T > 3) GAU_BODY(mx3, cx3, sx3)
        }
#undef GAU_BODY
    }
    // per-16-lane-group reduce: bins (A0+A1)+(A2+A3) via xor4,xor8;
    // lanes (L0+L2)+(L1+L3) via xor2,xor1 — identical tree to r15/r17.
    float r_[5] = {a0, a1, a2, a3, a4};
#pragma unroll
    for (int c = 0; c < 5; ++c) {
        float v = r_[c];
        v = v + __shfl_xor(v, 4);
        v = v + __shfl_xor(v, 8);
        v = v + __shfl_xor(v, 2);
        v = v + __shfl_xor(v, 1);
        r_[c] = v;
    }
    if (role == 1 && (tid & 15) == 0) {
#pragma unroll
        for (int c = 0; c < 5; ++c) cg[p][c] = r_[c];
    }
    __syncthreads();
    if (role == 0 && (tid & 15) == 0) {
#pragma unroll
        for (int c = 0; c < 5; ++c) combF[c * NN + n0] = r_[c] + cg[p][c];  // bil + gauss
    }
}

// ---------------- update: byte-identical to r13 ----------------
__global__ __launch_bounds__(256) void crf_update(const float* __restrict__ input,
                                                  const float* __restrict__ combF,
                                                  float4* __restrict__ qA,
                                                  float* __restrict__ qB,
                                                  float* __restrict__ outp,
                                                  int writeOut) {
#pragma clang fp contract(off)
    int n = blockIdx.x * 256 + threadIdx.x;
    if (n >= NN) return;
    int py = n / WW;
    int px = n - py * WW;
    float v[3][3][5];
#pragma unroll
    for (int ky = 0; ky < 3; ++ky) {
        int yy = py + ky - 1; yy = yy < 0 ? 0 : (yy > HH - 1 ? HH - 1 : yy);
#pragma unroll
        for (int kx = 0; kx < 3; ++kx) {
            int xx = px + kx - 1; xx = xx < 0 ? 0 : (xx > WW - 1 ? WW - 1 : xx);
            int m = yy * WW + xx;
#pragma unroll
            for (int c = 0; c < 5; ++c) v[ky][kx][c] = combF[c * NN + m];
        }
    }
    float l[5];
#pragma unroll
    for (int o = 0; o < 5; ++o) {
        float u = 0.f;
#pragma unroll
        for (int ky = 0; ky < 3; ++ky) {
#pragma unroll
            for (int kx = 0; kx < 3; ++kx) {
                float t = 0.f;                       // per-offset channel sum
#pragma unroll
                for (int ci = 0; ci < 5; ++ci)
                    if (ci != o) t = t + v[ky][kx][ci];
                u = u + t;                           // ascending offsets
            }
        }
        l[o] = input[o * NN + n] - 3.0f * u;
    }
    float m = fmaxf(fmaxf(fmaxf(fmaxf(l[0], l[1]), l[2]), l[3]), l[4]);
    float e0 = np_expf(l[0] - m), e1 = np_expf(l[1] - m), e2 = np_expf(l[2] - m);
    float e3 = np_expf(l[3] - m), e4 = np_expf(l[4] - m);
    float s = (((e0 + e1) + e2) + e3) + e4;
    float o0 = e0 / s, o1 = e1 / s, o2 = e2 / s, o3 = e3 / s, o4 = e4 / s;
    qA[n] = make_float4(o0, o1, o2, o3);
    qB[n] = o4;
    if (writeOut) {
        outp[0 * NN + n] = o0;
        outp[1 * NN + n] = o1;
        outp[2 * NN + n] = o2;
        outp[3 * NN + n] = o3;
        outp[4 * NN + n] = o4;
    }
}

extern "C" void kernel_launch(void* const* d_in, const int* in_sizes, int n_in,
                              void* d_out, int out_size, void* d_ws, size_t ws_size,
                              hipStream_t stream) {
    const float* input = (const float*)d_in[0];   // [1,5,96,96] f32
    const float* ref = (const float*)d_in[1];     // [1,3,96,96] f32
    float* ws = (float*)d_ws;
    float4* colA = (float4*)(ws + 0 * NN);        // 4*NN
    float4* qA = (float4*)(ws + 4 * NN);          // 4*NN
    float* qB = ws + 8 * NN;                      // NN
    float* combF = ws + 9 * NN;                   // 5*NN
    float* outp = (float*)d_out;

    crf_prep<<<36, 256, 0, stream>>>(input, ref, colA, qA, qB);
    for (int it = 0; it < 5; ++it) {
        crf_filter<<<1152, 256, 0, stream>>>(colA, qA, qB, combF);
        crf_update<<<36, 256, 0, stream>>>(input, combF, qA, qB, outp, it == 4 ? 1 : 0);
    }
}